// Round 1
// baseline (716.933 us; speedup 1.0000x reference)
//
#include <hip/hip_runtime.h>
#include <hip/hip_fp16.h>

// Problem constants (fixed by the reference)
#define BB     16
#define CIN    64
#define NN     40962
#define COUT   32
#define NEWN   (4*NN - 6)     // 163842

typedef _Float16 h2v __attribute__((ext_vector_type(2)));

__device__ __forceinline__ float dot2h(int a, int b, float c) {
#if __has_builtin(__builtin_amdgcn_fdot2)
  return __builtin_amdgcn_fdot2(__builtin_bit_cast(h2v, a),
                                __builtin_bit_cast(h2v, b), c, false);
#else
  h2v av = __builtin_bit_cast(h2v, a);
  h2v bv = __builtin_bit_cast(h2v, b);
  c += (float)av.x * (float)bv.x;
  c += (float)av.y * (float)bv.y;
  return c;
#endif
}

// ---------------- transpose: x (B,64,N) f32  ->  xT (B,N,64) f16 ----------------
// Makes every gathered column a contiguous 128B read instead of 64 strided lines.
__global__ __launch_bounds__(256) void k_transpose(const float* __restrict__ x,
                                                   __half* __restrict__ xT) {
  __shared__ float tile[64][65];          // +1 pad: conflict-free both phases
  const int b  = blockIdx.y;
  const int n0 = blockIdx.x * 64;
  const int lx = threadIdx.x & 63;
  const int ly = threadIdx.x >> 6;
  const float* xb = x + (size_t)b * CIN * NN;
  const int n = n0 + lx;
#pragma unroll
  for (int i = 0; i < 16; ++i) {
    int c = i * 4 + ly;
    tile[c][lx] = (n < NN) ? xb[(size_t)c * NN + n] : 0.f;   // coalesced read
  }
  __syncthreads();
  __half* xTb = xT + (size_t)b * NN * CIN;
#pragma unroll
  for (int i = 0; i < 16; ++i) {
    int nl = i * 4 + ly;
    int nn = n0 + nl;
    if (nn < NN) xTb[(size_t)nn * CIN + lx] = __float2half(tile[lx][nl]); // coalesced write
  }
}

// ---------------- fused gather + 64-dot kernel, f16 path ----------------
// W in LDS as f16 pairs, layout [t][co][pairs] with:
//   row pitch WP=36 dwords (16B aligned), t-slab pitch TP=32*36+4=1156 dwords.
// TP % 32 == 4  -> the 7 t-slabs start in distinct bank groups {4t..4t+3}, so a
// wave whose lanes carry different t does a conflict-free ds_read_b128 (lanes
// sharing t broadcast).
#define WP 36
#define TP (32*WP + 4)

__global__ __launch_bounds__(256) void k_upconv_f16(
    const __half* __restrict__ xT, const float* __restrict__ W,
    const float* __restrict__ bias, const int* __restrict__ top,
    const int* __restrict__ down, float* __restrict__ out) {
  __shared__ int   wl[7 * TP];     // ~32.4 KB
  __shared__ float bl[224];
  const int tid = threadIdx.x;

  // Stage W (224x64 f32) -> f16 pairs in LDS, [t][co][cp]
  for (int p = tid; p < 224 * 32; p += 256) {
    int o  = p >> 5;               // 0..223 ; o = co*7 + t
    int cp = p & 31;               // pair index 0..31
    h2v h;
    h.x = (_Float16)W[o * 64 + 2 * cp];
    h.y = (_Float16)W[o * 64 + 2 * cp + 1];
    wl[(o % 7) * TP + (o / 7) * WP + cp] = __builtin_bit_cast(int, h);
  }
  if (tid < 224) bl[tid] = bias[tid];
  __syncthreads();

  const int b = blockIdx.y;
  const int k = blockIdx.x * 256 + tid;

  int nit = 0, t0 = 0, t1 = 0, n0 = 0, n1 = 0;
  if (k < NEWN) {
    if (k < NN) {                       // x1 region: single gather
      int j = top[k];
      t0 = j / NN; n0 = j - t0 * NN;
      nit = 1;
    } else {                            // x2 region: mean of two gathers
      int kk = k - NN;
      int j1 = down[2 * kk];
      int j2 = down[2 * kk + 1];
      t0 = j1 / NN; n0 = j1 - t0 * NN;
      t1 = j2 / NN; n1 = j2 - t1 * NN;
      nit = 2;
    }
  }

  float acc[32];
#pragma unroll
  for (int i = 0; i < 32; ++i) acc[i] = 0.f;

  const __half* xTb = xT + (size_t)b * NN * CIN;
  for (int it = 0; it < nit; ++it) {
    const int t = it ? t1 : t0;
    const int n = it ? n1 : n0;
    const int4* col = (const int4*)(xTb + (size_t)n * CIN); // contiguous 128B column
    const int base = t * TP;
#pragma unroll
    for (int hf = 0; hf < 2; ++hf) {    // two 64B halves of the column
      int4 xv[4];
#pragma unroll
      for (int q = 0; q < 4; ++q) xv[q] = col[hf * 4 + q];  // 4 loads in flight
#pragma unroll
      for (int co = 0; co < 32; ++co) {
        float a = acc[co];
#pragma unroll
        for (int q = 0; q < 4; ++q) {
          int4 wv = *(const int4*)&wl[base + co * WP + (hf * 4 + q) * 4];
          a = dot2h(wv.x, xv[q].x, a);
          a = dot2h(wv.y, xv[q].y, a);
          a = dot2h(wv.z, xv[q].z, a);
          a = dot2h(wv.w, xv[q].w, a);
        }
        acc[co] = a;
      }
    }
  }

  if (k < NEWN) {
    float* ob = out + (size_t)b * COUT * NEWN + k;          // coalesced per co
    if (k < NN) {
#pragma unroll
      for (int co = 0; co < 32; ++co)
        ob[(size_t)co * NEWN] = acc[co] + bl[co * 7 + t0];
    } else {
#pragma unroll
      for (int co = 0; co < 32; ++co)
        ob[(size_t)co * NEWN] = 0.5f * (acc[co] + bl[co * 7 + t0] + bl[co * 7 + t1]);
    }
  }
}

// ---------------- fallback (workspace too small): fp32, strided x reads ----------------
#define WPB 68
#define TPB (32*WPB + 4)   // 2180 dwords; 2180%32==4 -> same t-bank trick

__global__ __launch_bounds__(256) void k_upconv_f32(
    const float* __restrict__ x, const float* __restrict__ W,
    const float* __restrict__ bias, const int* __restrict__ top,
    const int* __restrict__ down, float* __restrict__ out) {
  __shared__ float wl[7 * TPB];   // ~61 KB
  __shared__ float bl[224];
  const int tid = threadIdx.x;
  for (int p = tid; p < 224 * 64; p += 256) {
    int o = p >> 6, c = p & 63;
    wl[(o % 7) * TPB + (o / 7) * WPB + c] = W[p];
  }
  if (tid < 224) bl[tid] = bias[tid];
  __syncthreads();

  const int b = blockIdx.y;
  const int k = blockIdx.x * 256 + tid;

  int nit = 0, t0 = 0, t1 = 0, n0 = 0, n1 = 0;
  if (k < NEWN) {
    if (k < NN) {
      int j = top[k];
      t0 = j / NN; n0 = j - t0 * NN; nit = 1;
    } else {
      int kk = k - NN;
      int j1 = down[2 * kk], j2 = down[2 * kk + 1];
      t0 = j1 / NN; n0 = j1 - t0 * NN;
      t1 = j2 / NN; n1 = j2 - t1 * NN;
      nit = 2;
    }
  }

  float acc[32];
#pragma unroll
  for (int i = 0; i < 32; ++i) acc[i] = 0.f;

  for (int it = 0; it < nit; ++it) {
    const int t = it ? t1 : t0;
    const int n = it ? n1 : n0;
    const float* col = x + (size_t)b * CIN * NN + n;
    const int base = t * TPB;
#pragma unroll
    for (int ch = 0; ch < 8; ++ch) {          // 8 chunks of 8 channels
      float xv[8];
#pragma unroll
      for (int q = 0; q < 8; ++q) xv[q] = col[(size_t)(ch * 8 + q) * NN];
#pragma unroll
      for (int co = 0; co < 32; ++co) {
        float a = acc[co];
        const float* wr = &wl[base + co * WPB + ch * 8];
        float4 w0 = *(const float4*)(wr);
        float4 w1 = *(const float4*)(wr + 4);
        a += w0.x * xv[0]; a += w0.y * xv[1]; a += w0.z * xv[2]; a += w0.w * xv[3];
        a += w1.x * xv[4]; a += w1.y * xv[5]; a += w1.z * xv[6]; a += w1.w * xv[7];
        acc[co] = a;
      }
    }
  }

  if (k < NEWN) {
    float* ob = out + (size_t)b * COUT * NEWN + k;
    if (k < NN) {
#pragma unroll
      for (int co = 0; co < 32; ++co)
        ob[(size_t)co * NEWN] = acc[co] + bl[co * 7 + t0];
    } else {
#pragma unroll
      for (int co = 0; co < 32; ++co)
        ob[(size_t)co * NEWN] = 0.5f * (acc[co] + bl[co * 7 + t0] + bl[co * 7 + t1]);
    }
  }
}

extern "C" void kernel_launch(void* const* d_in, const int* in_sizes, int n_in,
                              void* d_out, int out_size, void* d_ws, size_t ws_size,
                              hipStream_t stream) {
  const float* x    = (const float*)d_in[0];
  const float* W    = (const float*)d_in[1];
  const float* bias = (const float*)d_in[2];
  const int*   top  = (const int*)d_in[3];
  const int*   down = (const int*)d_in[4];
  float* out = (float*)d_out;

  const size_t xT_bytes = (size_t)BB * NN * CIN * sizeof(__half);  // ~84 MB
  if (ws_size >= xT_bytes) {
    __half* xT = (__half*)d_ws;
    k_transpose<<<dim3((NN + 63) / 64, BB), 256, 0, stream>>>(x, xT);
    k_upconv_f16<<<dim3((NEWN + 255) / 256, BB), 256, 0, stream>>>(xT, W, bias, top, down, out);
  } else {
    k_upconv_f32<<<dim3((NEWN + 255) / 256, BB), 256, 0, stream>>>(x, W, bias, top, down, out);
  }
}

// Round 2
// 614.559 us; speedup vs baseline: 1.1666x; 1.1666x over previous
//
#include <hip/hip_runtime.h>
#include <hip/hip_fp16.h>

// Problem constants (fixed by the reference)
#define BB     16
#define CIN    64
#define NN     40962
#define COUT   32
#define NEWN   (4*NN - 6)            // 163842
#define GROUPS_PER_B ((NEWN + 31)/32) // 5121
#define NGROUPS (BB * GROUPS_PER_B)   // 81936

typedef _Float16 f16x8  __attribute__((ext_vector_type(8)));
typedef float    f32x16 __attribute__((ext_vector_type(16)));
typedef _Float16 h2     __attribute__((ext_vector_type(2)));

__device__ __forceinline__ int pk_add_h2(int a, int b) {
  h2 r = __builtin_bit_cast(h2, a) + __builtin_bit_cast(h2, b);
  return __builtin_bit_cast(int, r);
}
__device__ __forceinline__ int pack2(float lo, float hi) {
  h2 r; r.x = (_Float16)lo; r.y = (_Float16)hi;
  return __builtin_bit_cast(int, r);
}

// ---------------- transpose: x (B,64,N) f32  ->  xT (B,N,64) f16 ----------------
__global__ __launch_bounds__(256) void k_transpose(const float* __restrict__ x,
                                                   __half* __restrict__ xT) {
  __shared__ float tile[64][65];
  const int b  = blockIdx.y;
  const int n0 = blockIdx.x * 64;
  const int lx = threadIdx.x & 63;
  const int ly = threadIdx.x >> 6;
  const float* xb = x + (size_t)b * CIN * NN;
  const int n = n0 + lx;
#pragma unroll
  for (int i = 0; i < 16; ++i) {
    int c = i * 4 + ly;
    tile[c][lx] = (n < NN) ? xb[(size_t)c * NN + n] : 0.f;
  }
  __syncthreads();
  __half* xTb = xT + (size_t)b * NN * CIN;
#pragma unroll
  for (int i = 0; i < 16; ++i) {
    int nl = i * 4 + ly;
    int nn = n0 + nl;
    if (nn < NN) xTb[(size_t)nn * CIN + lx] = __float2half(tile[lx][nl]);
  }
}

// ---------------- MFMA compute: sparse-K=448(+8 bias) GEMM, W register-resident --------
// Per wave-group: 32 output slots. D[co][slot] via v_mfma_f32_32x32x16_f16.
// A (M=co=32, K=464): A[co][t*64+c] = 0.5*W[co*7+t][c]; A[co][448+tau] = 0.5*b[co*7+tau].
// B (K=464, N=slot=32): gathered xT columns placed in their t-slab; selector chunk for bias.
// Fragment layout (32x32x16 f16): A[m=lane&31][k=(lane>>5)*8+j], B[k][n=lane&31] same k-map,
// D: col=lane&31 (slot), row(co)=(reg&3)+8*(reg>>2)+4*(lane>>5).
__global__ __launch_bounds__(256, 2) void k_upconv_mfma(
    const __half* __restrict__ xT, const float* __restrict__ W,
    const float* __restrict__ bias, const int* __restrict__ top,
    const int* __restrict__ down, float* __restrict__ out) {
  const int lane = threadIdx.x & 63;
  const int co   = lane & 31;        // A row (M)
  const int h    = lane >> 5;        // k-half
  const int waveInBlock = threadIdx.x >> 6;
  const int gwave = blockIdx.x * (blockDim.x >> 6) + waveInBlock;
  const int nwaves = gridDim.x * (blockDim.x >> 6);

  // ---- Load resident A fragments: 29 steps x 4 dwords = 116 VGPRs ----
  int4 Af[29];
#pragma unroll
  for (int s = 0; s < 28; ++s) {
    const int t  = s >> 2;
    const int c0 = 16 * (s & 3) + 8 * h;
    const float* wr = W + (co * 7 + t) * 64 + c0;
    float4 wa = *(const float4*)wr;
    float4 wb = *(const float4*)(wr + 4);
    Af[s].x = pack2(0.5f * wa.x, 0.5f * wa.y);
    Af[s].y = pack2(0.5f * wa.z, 0.5f * wa.w);
    Af[s].z = pack2(0.5f * wb.x, 0.5f * wb.y);
    Af[s].w = pack2(0.5f * wb.z, 0.5f * wb.w);
  }
  {
    int4 ab = {0, 0, 0, 0};
    if (h == 0) {
      float bv[8];
#pragma unroll
      for (int tau = 0; tau < 7; ++tau) bv[tau] = 0.5f * bias[co * 7 + tau];
      bv[7] = 0.f;
      ab.x = pack2(bv[0], bv[1]);
      ab.y = pack2(bv[2], bv[3]);
      ab.z = pack2(bv[4], bv[5]);
      ab.w = pack2(bv[6], bv[7]);
    }
    Af[28] = ab;
  }

  for (int gid = gwave; gid < NGROUPS; gid += nwaves) {
    const int b = gid / GROUPS_PER_B;
    const int g = gid - b * GROUPS_PER_B;
    const int k = g * 32 + co;            // this lane's slot (both halves same slot)
    const bool valid = (k < NEWN);

    int j1 = 0, j2 = 0;
    if (valid) {
      if (k < NN) { j1 = top[k]; j2 = j1; }
      else {
        const int kk = k - NN;
        j1 = down[2 * kk];
        j2 = down[2 * kk + 1];
      }
    }
    const int t0 = j1 / NN, n0 = j1 - t0 * NN;
    const int t1 = j2 / NN, n1 = j2 - t1 * NN;

    // Gather this slot's two columns: 4 x 16B chunks each (this half's k-range)
    const __half* xTb = xT + (size_t)b * NN * CIN;
    const int4* base0 = (const int4*)(xTb + (size_t)n0 * CIN);
    const int4* base1 = (const int4*)(xTb + (size_t)n1 * CIN);
    int4 col0[4], col1[4];
#pragma unroll
    for (int q = 0; q < 4; ++q) col0[q] = base0[2 * q + h];
#pragma unroll
    for (int q = 0; q < 4; ++q) col1[q] = base1[2 * q + h];

    f32x16 acc;
#pragma unroll
    for (int i = 0; i < 16; ++i) acc[i] = 0.f;

    // ---- main K loop: 28 data steps ----
#pragma unroll
    for (int s = 0; s < 28; ++s) {
      const int t = s >> 2, q = s & 3;
      const bool m0 = (t0 == t), m1 = (t1 == t);
      int4 bb;
      bb.x = pk_add_h2(m0 ? col0[q].x : 0, m1 ? col1[q].x : 0);
      bb.y = pk_add_h2(m0 ? col0[q].y : 0, m1 ? col1[q].y : 0);
      bb.z = pk_add_h2(m0 ? col0[q].z : 0, m1 ? col1[q].z : 0);
      bb.w = pk_add_h2(m0 ? col0[q].w : 0, m1 ? col1[q].w : 0);
      acc = __builtin_amdgcn_mfma_f32_32x32x16_f16(
          __builtin_bit_cast(f16x8, Af[s]), __builtin_bit_cast(f16x8, bb), acc, 0, 0, 0);
    }

    // ---- bias step: selector chunk on B ----
    {
      int4 bsel = {0, 0, 0, 0};
      if (h == 0) {
        float c0f = (float)((t0 == 0) + (t1 == 0));
        float c1f = (float)((t0 == 1) + (t1 == 1));
        float c2f = (float)((t0 == 2) + (t1 == 2));
        float c3f = (float)((t0 == 3) + (t1 == 3));
        float c4f = (float)((t0 == 4) + (t1 == 4));
        float c5f = (float)((t0 == 5) + (t1 == 5));
        float c6f = (float)((t0 == 6) + (t1 == 6));
        bsel.x = pack2(c0f, c1f);
        bsel.y = pack2(c2f, c3f);
        bsel.z = pack2(c4f, c5f);
        bsel.w = pack2(c6f, 0.f);
      }
      acc = __builtin_amdgcn_mfma_f32_32x32x16_f16(
          __builtin_bit_cast(f16x8, Af[28]), __builtin_bit_cast(f16x8, bsel), acc, 0, 0, 0);
    }

    // ---- store: D[co_row][slot], slot = lane&31 -> coalesced 128B segments ----
    if (valid) {
      float* ob = out + (size_t)b * COUT * NEWN + k;
#pragma unroll
      for (int r = 0; r < 16; ++r) {
        const int corow = (r & 3) + 8 * (r >> 2) + 4 * h;
        ob[(size_t)corow * NEWN] = acc[r];
      }
    }
  }
}

// ---------------- fallback (workspace too small): fp32, strided x reads ----------------
#define WPB 68
#define TPB (32*WPB + 4)

__global__ __launch_bounds__(256) void k_upconv_f32(
    const float* __restrict__ x, const float* __restrict__ W,
    const float* __restrict__ bias, const int* __restrict__ top,
    const int* __restrict__ down, float* __restrict__ out) {
  __shared__ float wl[7 * TPB];
  __shared__ float bl[224];
  const int tid = threadIdx.x;
  for (int p = tid; p < 224 * 64; p += 256) {
    int o = p >> 6, c = p & 63;
    wl[(o % 7) * TPB + (o / 7) * WPB + c] = W[p];
  }
  if (tid < 224) bl[tid] = bias[tid];
  __syncthreads();

  const int b = blockIdx.y;
  const int k = blockIdx.x * 256 + tid;

  int nit = 0, t0 = 0, t1 = 0, n0 = 0, n1 = 0;
  if (k < NEWN) {
    if (k < NN) {
      int j = top[k];
      t0 = j / NN; n0 = j - t0 * NN; nit = 1;
    } else {
      int kk = k - NN;
      int j1 = down[2 * kk], j2 = down[2 * kk + 1];
      t0 = j1 / NN; n0 = j1 - t0 * NN;
      t1 = j2 / NN; n1 = j2 - t1 * NN;
      nit = 2;
    }
  }

  float acc[32];
#pragma unroll
  for (int i = 0; i < 32; ++i) acc[i] = 0.f;

  for (int it = 0; it < nit; ++it) {
    const int t = it ? t1 : t0;
    const int n = it ? n1 : n0;
    const float* col = x + (size_t)b * CIN * NN + n;
    const int base = t * TPB;
#pragma unroll
    for (int ch = 0; ch < 8; ++ch) {
      float xv[8];
#pragma unroll
      for (int q = 0; q < 8; ++q) xv[q] = col[(size_t)(ch * 8 + q) * NN];
#pragma unroll
      for (int co = 0; co < 32; ++co) {
        float a = acc[co];
        const float* wr = &wl[base + co * WPB + ch * 8];
        float4 w0 = *(const float4*)(wr);
        float4 w1 = *(const float4*)(wr + 4);
        a += w0.x * xv[0]; a += w0.y * xv[1]; a += w0.z * xv[2]; a += w0.w * xv[3];
        a += w1.x * xv[4]; a += w1.y * xv[5]; a += w1.z * xv[6]; a += w1.w * xv[7];
        acc[co] = a;
      }
    }
  }

  if (k < NEWN) {
    float* ob = out + (size_t)b * COUT * NEWN + k;
    if (k < NN) {
#pragma unroll
      for (int co = 0; co < 32; ++co)
        ob[(size_t)co * NEWN] = acc[co] + bl[co * 7 + t0];
    } else {
#pragma unroll
      for (int co = 0; co < 32; ++co)
        ob[(size_t)co * NEWN] = 0.5f * (acc[co] + bl[co * 7 + t0] + bl[co * 7 + t1]);
    }
  }
}

extern "C" void kernel_launch(void* const* d_in, const int* in_sizes, int n_in,
                              void* d_out, int out_size, void* d_ws, size_t ws_size,
                              hipStream_t stream) {
  const float* x    = (const float*)d_in[0];
  const float* W    = (const float*)d_in[1];
  const float* bias = (const float*)d_in[2];
  const int*   top  = (const int*)d_in[3];
  const int*   down = (const int*)d_in[4];
  float* out = (float*)d_out;

  const size_t xT_bytes = (size_t)BB * NN * CIN * sizeof(__half);  // ~84 MB
  if (ws_size >= xT_bytes) {
    __half* xT = (__half*)d_ws;
    k_transpose<<<dim3((NN + 63) / 64, BB), 256, 0, stream>>>(x, xT);
    k_upconv_mfma<<<dim3(512), 256, 0, stream>>>(xT, W, bias, top, down, out);
  } else {
    k_upconv_f32<<<dim3((NEWN + 255) / 256, BB), 256, 0, stream>>>(x, W, bias, top, down, out);
  }
}